// Round 4
// baseline (235.249 us; speedup 1.0000x reference)
//
#include <hip/hip_runtime.h>
#include <stdint.h>

typedef __attribute__((ext_vector_type(8))) short short8v;
typedef __attribute__((ext_vector_type(4))) float float4v;

__device__ __forceinline__ unsigned short f32_to_bf16(float f) {
    union { float f; uint32_t u; } v; v.f = f;
    uint32_t u = v.u;
    u += 0x7FFFu + ((u >> 16) & 1u);
    return (unsigned short)(u >> 16);
}

#define T_LEN 4096
#define C_DIM 1024
#define HSZ 64

// ---------------- kernel 0: W -> Wt (bf16, transposed [192][1024]) ----------------
__global__ void wt_kernel(const float* __restrict__ Wq, const float* __restrict__ Wk,
                          const float* __restrict__ Wv, unsigned short* __restrict__ Wt) {
    int tid = blockIdx.x * blockDim.x + threadIdx.x;   // 0 .. 3*65536-1
    int m   = tid >> 16;
    int rem = tid & 65535;
    int kk  = rem >> 6;
    int col = rem & 63;
    const float* W = (m == 0) ? Wq : ((m == 1) ? Wk : Wv);
    Wt[(size_t)m * 65536 + (size_t)col * 1024 + kk] = f32_to_bf16(W[(size_t)kk * 64 + col]);
}

// ---------------- kernel 1: fused QKV projection ----------------
// q, k written [B*T][64] row-major; v written TRANSPOSED: vT[b][d][t] ([B][64][4096])
#define XLD 1032   // 1024 + 8 pad

__global__ __launch_bounds__(256) void qkv_kernel(
    const float* __restrict__ x, const unsigned short* __restrict__ Wt,
    unsigned short* __restrict__ qo, unsigned short* __restrict__ ko,
    unsigned short* __restrict__ vto)
{
    __shared__ __align__(16) unsigned short xs[16 * XLD];
    const int tid  = threadIdx.x;
    const int row0 = blockIdx.x * 16;

    #pragma unroll
    for (int i = 0; i < 16; ++i) {
        int f   = i * 256 + tid;           // float4 index, 4096 total
        int row = f >> 8, c4 = f & 255;
        const float4 val = *((const float4*)x + (size_t)(row0 + row) * 256 + c4);
        union { unsigned short s[4]; uint64_t u; } pk;
        pk.s[0] = f32_to_bf16(val.x); pk.s[1] = f32_to_bf16(val.y);
        pk.s[2] = f32_to_bf16(val.z); pk.s[3] = f32_to_bf16(val.w);
        *(uint64_t*)(&xs[row * XLD + c4 * 4]) = pk.u;
    }
    __syncthreads();

    const int wave = tid >> 6, lane = tid & 63;
    const int g = lane >> 4, c = lane & 15;

    float4v acc0 = {0,0,0,0}, acc1 = {0,0,0,0}, acc2 = {0,0,0,0};
    #pragma unroll 4
    for (int ks = 0; ks < 32; ++ks) {
        const int koff = ks * 32 + g * 8;
        short8v a  = *(const short8v*)(&xs[c * XLD + koff]);
        short8v b0 = *(const short8v*)(&Wt[(size_t)((wave*3+0)*16 + c) * 1024 + koff]);
        short8v b1 = *(const short8v*)(&Wt[(size_t)((wave*3+1)*16 + c) * 1024 + koff]);
        short8v b2 = *(const short8v*)(&Wt[(size_t)((wave*3+2)*16 + c) * 1024 + koff]);
        acc0 = __builtin_amdgcn_mfma_f32_16x16x32_bf16(a, b0, acc0, 0, 0, 0);
        acc1 = __builtin_amdgcn_mfma_f32_16x16x32_bf16(a, b1, acc1, 0, 0, 0);
        acc2 = __builtin_amdgcn_mfma_f32_16x16x32_bf16(a, b2, acc2, 0, 0, 0);
    }

    float4v accs[3] = {acc0, acc1, acc2};
    #pragma unroll
    for (int t = 0; t < 3; ++t) {
        int ct = wave * 3 + t;
        int m = ct >> 2, hcol = (ct & 3) * 16 + c;
        if (m == 2) {
            // vT[b][hcol][t_global]
            #pragma unroll
            for (int j = 0; j < 4; ++j) {
                int r = row0 + g * 4 + j;
                vto[((size_t)(r >> 12) * 64 + hcol) * 4096 + (r & 4095)] = f32_to_bf16(accs[t][j]);
            }
        } else {
            unsigned short* dst = (m == 0) ? qo : ko;
            float sc = (m == 0) ? 0.125f : 1.0f;   // fold 1/sqrt(64) into q
            #pragma unroll
            for (int j = 0; j < 4; ++j)
                dst[(size_t)(row0 + g * 4 + j) * 64 + hcol] = f32_to_bf16(accs[t][j] * sc);
        }
    }
}

// ---------------- kernel 2: causal flash attention ----------------
#define KLD 72    // K tile rows: 144 B stride, 16B-aligned b128 frag reads
#define VTLD 72   // vT tile rows (d-major): same stride
#define PLD 72

__global__ __launch_bounds__(128) void attn_kernel(
    const unsigned short* __restrict__ qi, const unsigned short* __restrict__ ki,
    const unsigned short* __restrict__ vt, float* __restrict__ out)
{
    // double-buffered K (row-major [s][d]) and vT (row-major [d][s])
    __shared__ __align__(16) unsigned short Ks[2][64 * KLD];
    __shared__ __align__(16) unsigned short Vt[2][64 * VTLD];
    __shared__ __align__(16) unsigned short Ps[2][16 * PLD];   // per-wave P, q-row-major

    const int tid  = threadIdx.x;
    const int wave = tid >> 6, lane = tid & 63;
    const int g = lane >> 4, c = lane & 15;
    const int b = blockIdx.y;
    const int qb = 127 - (int)blockIdx.x;       // LPT: longest q-strips first
    const int rbase = qb * 32 + wave * 16;
    const size_t bo = (size_t)b * T_LEN * HSZ;  // q/k/out batch offset; vT has same batch size

    short8v qf0 = *(const short8v*)(qi + bo + (size_t)(rbase + c) * 64 +  0 + g * 8);
    short8v qf1 = *(const short8v*)(qi + bo + (size_t)(rbase + c) * 64 + 32 + g * 8);

    float4v acc[4];
    #pragma unroll
    for (int i2 = 0; i2 < 4; ++i2) acc[i2] = (float4v){0,0,0,0};
    float mrow[4] = {-3e38f, -3e38f, -3e38f, -3e38f};
    float lsum[4] = {0.f, 0.f, 0.f, 0.f};      // per-lane partial row sums
    const int nt = (qb * 32 + 32 + 63) >> 6;

    // per-thread staging coords: 4 K chunks ([s][d]) + 4 vT chunks ([d][s])
    int sA[4], dA[4];
    #pragma unroll
    for (int i = 0; i < 4; ++i) {
        int idx = i * 128 + tid;
        sA[i] = idx >> 3; dA[i] = (idx & 7) * 8;   // K: row sA, col dA | vT: row dA? no: dV=sA, sV=dA
    }

    uint4 kr[4], vr[4];
    #pragma unroll
    for (int i = 0; i < 4; ++i) {
        kr[i] = *(const uint4*)(ki + bo + (size_t)sA[i] * 64 + dA[i]);
        vr[i] = *(const uint4*)(vt + bo + (size_t)sA[i] * 4096 + dA[i]);   // row d=sA[i], cols dA[i]..+7
    }
    #pragma unroll
    for (int i = 0; i < 4; ++i) {
        *(uint4*)(&Ks[0][sA[i] * KLD  + dA[i]]) = kr[i];
        *(uint4*)(&Vt[0][sA[i] * VTLD + dA[i]]) = vr[i];
    }
    __syncthreads();

    unsigned short* Pw = &Ps[wave][0];

    for (int t = 0; t < nt; ++t) {
        const int buf = t & 1;
        const int s0  = t * 64;

        // prefetch next tile into registers (latency hides under compute)
        if (t + 1 < nt) {
            const int so = s0 + 64;
            #pragma unroll
            for (int i = 0; i < 4; ++i) {
                kr[i] = *(const uint4*)(ki + bo + (size_t)(so + sA[i]) * 64 + dA[i]);
                vr[i] = *(const uint4*)(vt + bo + (size_t)sA[i] * 4096 + so + dA[i]);
            }
        }

        // ---- S = Q K^T ----
        const unsigned short* Kb = &Ks[buf][0];
        float4v sa[4];
        #pragma unroll
        for (int ct = 0; ct < 4; ++ct) {
            short8v b0 = *(const short8v*)(&Kb[(ct * 16 + c) * KLD +  0 + g * 8]);
            short8v b1 = *(const short8v*)(&Kb[(ct * 16 + c) * KLD + 32 + g * 8]);
            float4v z = {0, 0, 0, 0};
            z = __builtin_amdgcn_mfma_f32_16x16x32_bf16(qf0, b0, z, 0, 0, 0);
            sa[ct] = __builtin_amdgcn_mfma_f32_16x16x32_bf16(qf1, b1, z, 0, 0, 0);
        }

        // ---- causal mask ----
        if (s0 + 63 > rbase) {
            #pragma unroll
            for (int ct = 0; ct < 4; ++ct)
                #pragma unroll
                for (int j = 0; j < 4; ++j)
                    if (s0 + ct * 16 + c > rbase + g * 4 + j) sa[ct][j] = -3e38f;
        }

        // ---- online softmax (cross-lane sum deferred to epilogue) ----
        #pragma unroll
        for (int j = 0; j < 4; ++j) {
            float mx = fmaxf(fmaxf(sa[0][j], sa[1][j]), fmaxf(sa[2][j], sa[3][j]));
            #pragma unroll
            for (int sh = 1; sh < 16; sh <<= 1) mx = fmaxf(mx, __shfl_xor(mx, sh, 64));
            const float nm = fmaxf(mrow[j], mx);
            const float al = __expf(mrow[j] - nm);
            mrow[j] = nm;
            float ps = 0.f;
            #pragma unroll
            for (int ct = 0; ct < 4; ++ct) {
                float p = __expf(sa[ct][j] - nm);
                sa[ct][j] = p;
                ps += p;
            }
            lsum[j] = lsum[j] * al + ps;
            #pragma unroll
            for (int ct = 0; ct < 4; ++ct) acc[ct][j] *= al;
        }

        // ---- P (D-layout) -> per-wave LDS -> A-fragment layout (R2-verified path) ----
        #pragma unroll
        for (int ct = 0; ct < 4; ++ct)
            #pragma unroll
            for (int j = 0; j < 4; ++j)
                Pw[(g * 4 + j) * PLD + ct * 16 + c] = f32_to_bf16(sa[ct][j]);

        short8v pa0 = *(const short8v*)(&Pw[c * PLD +  0 + g * 8]);
        short8v pa1 = *(const short8v*)(&Pw[c * PLD + 32 + g * 8]);

        // ---- O += P V : B-frag = 8 contiguous elements of a vT row ----
        const unsigned short* Vb = &Vt[buf][0];
        #pragma unroll
        for (int ct = 0; ct < 4; ++ct) {
            short8v v0 = *(const short8v*)(&Vb[(ct * 16 + c) * VTLD +  0 + g * 8]);
            acc[ct] = __builtin_amdgcn_mfma_f32_16x16x32_bf16(pa0, v0, acc[ct], 0, 0, 0);
        }
        #pragma unroll
        for (int ct = 0; ct < 4; ++ct) {
            short8v v1 = *(const short8v*)(&Vb[(ct * 16 + c) * VTLD + 32 + g * 8]);
            acc[ct] = __builtin_amdgcn_mfma_f32_16x16x32_bf16(pa1, v1, acc[ct], 0, 0, 0);
        }

        // ---- write prefetched tile to the other buffer ----
        if (t + 1 < nt) {
            #pragma unroll
            for (int i = 0; i < 4; ++i) {
                *(uint4*)(&Ks[buf ^ 1][sA[i] * KLD  + dA[i]]) = kr[i];
                *(uint4*)(&Vt[buf ^ 1][sA[i] * VTLD + dA[i]]) = vr[i];
            }
        }
        __syncthreads();   // single barrier per tile (hazard-analyzed)
    }

    // ---- epilogue: reduce row sums across the 16 c-lanes, divide ----
    #pragma unroll
    for (int j = 0; j < 4; ++j) {
        float l = lsum[j];
        #pragma unroll
        for (int sh = 1; sh < 16; sh <<= 1) l += __shfl_xor(l, sh, 64);
        lsum[j] = l;
    }
    #pragma unroll
    for (int ct = 0; ct < 4; ++ct)
        #pragma unroll
        for (int j = 0; j < 4; ++j)
            out[bo + (size_t)(rbase + g * 4 + j) * 64 + ct * 16 + c] = acc[ct][j] / lsum[j];
}

extern "C" void kernel_launch(void* const* d_in, const int* in_sizes, int n_in,
                              void* d_out, int out_size, void* d_ws, size_t ws_size,
                              hipStream_t stream) {
    const float* x  = (const float*)d_in[0];
    const float* Wq = (const float*)d_in[1];
    const float* Wk = (const float*)d_in[2];
    const float* Wv = (const float*)d_in[3];

    unsigned short* Wt = (unsigned short*)d_ws;                        // 384 KiB
    unsigned short* q  = (unsigned short*)((char*)d_ws + (size_t)3 * 65536 * 2);
    unsigned short* k  = q + (size_t)4 * T_LEN * HSZ;
    unsigned short* vT = k + (size_t)4 * T_LEN * HSZ;                  // [B][64][4096]
    float* out = (float*)d_out;

    hipLaunchKernelGGL(wt_kernel,  dim3(768),     dim3(256), 0, stream, Wq, Wk, Wv, Wt);
    hipLaunchKernelGGL(qkv_kernel, dim3(1024),    dim3(256), 0, stream, x, Wt, q, k, vT);
    hipLaunchKernelGGL(attn_kernel, dim3(128, 4), dim3(128), 0, stream, q, k, vT, out);
}

// Round 5
// 123.410 us; speedup vs baseline: 1.9062x; 1.9062x over previous
//
#include <hip/hip_runtime.h>
#include <stdint.h>

typedef __attribute__((ext_vector_type(8))) short short8v;
typedef __attribute__((ext_vector_type(4))) float float4v;

__device__ __forceinline__ unsigned short f32_to_bf16(float f) {
    union { float f; uint32_t u; } v; v.f = f;
    uint32_t u = v.u;
    u += 0x7FFFu + ((u >> 16) & 1u);
    return (unsigned short)(u >> 16);
}

#define T_LEN 4096
#define C_DIM 1024
#define HSZ 64

// ---------------- kernel 0: W -> Wt (bf16, transposed [192][1024]) ----------------
__global__ void wt_kernel(const float* __restrict__ Wq, const float* __restrict__ Wk,
                          const float* __restrict__ Wv, unsigned short* __restrict__ Wt) {
    int tid = blockIdx.x * blockDim.x + threadIdx.x;   // 0 .. 3*65536-1
    int m   = tid >> 16;
    int rem = tid & 65535;
    int kk  = rem >> 6;
    int col = rem & 63;
    const float* W = (m == 0) ? Wq : ((m == 1) ? Wk : Wv);
    Wt[(size_t)m * 65536 + (size_t)col * 1024 + kk] = f32_to_bf16(W[(size_t)kk * 64 + col]);
}

// ---------------- kernel 1: fused QKV projection ----------------
// q, k written [B*T][64] row-major; v written TRANSPOSED: vT[b][d][t] ([B][64][4096])
#define XLD 1032   // 1024 + 8 pad

__global__ __launch_bounds__(256) void qkv_kernel(
    const float* __restrict__ x, const unsigned short* __restrict__ Wt,
    unsigned short* __restrict__ qo, unsigned short* __restrict__ ko,
    unsigned short* __restrict__ vto)
{
    __shared__ __align__(16) unsigned short xs[16 * XLD];
    const int tid  = threadIdx.x;
    const int row0 = blockIdx.x * 16;

    #pragma unroll
    for (int i = 0; i < 16; ++i) {
        int f   = i * 256 + tid;           // float4 index, 4096 total
        int row = f >> 8, c4 = f & 255;
        const float4 val = *((const float4*)x + (size_t)(row0 + row) * 256 + c4);
        union { unsigned short s[4]; uint64_t u; } pk;
        pk.s[0] = f32_to_bf16(val.x); pk.s[1] = f32_to_bf16(val.y);
        pk.s[2] = f32_to_bf16(val.z); pk.s[3] = f32_to_bf16(val.w);
        *(uint64_t*)(&xs[row * XLD + c4 * 4]) = pk.u;
    }
    __syncthreads();

    const int wave = tid >> 6, lane = tid & 63;
    const int g = lane >> 4, c = lane & 15;

    float4v acc0 = {0,0,0,0}, acc1 = {0,0,0,0}, acc2 = {0,0,0,0};
    #pragma unroll 4
    for (int ks = 0; ks < 32; ++ks) {
        const int koff = ks * 32 + g * 8;
        short8v a  = *(const short8v*)(&xs[c * XLD + koff]);
        short8v b0 = *(const short8v*)(&Wt[(size_t)((wave*3+0)*16 + c) * 1024 + koff]);
        short8v b1 = *(const short8v*)(&Wt[(size_t)((wave*3+1)*16 + c) * 1024 + koff]);
        short8v b2 = *(const short8v*)(&Wt[(size_t)((wave*3+2)*16 + c) * 1024 + koff]);
        acc0 = __builtin_amdgcn_mfma_f32_16x16x32_bf16(a, b0, acc0, 0, 0, 0);
        acc1 = __builtin_amdgcn_mfma_f32_16x16x32_bf16(a, b1, acc1, 0, 0, 0);
        acc2 = __builtin_amdgcn_mfma_f32_16x16x32_bf16(a, b2, acc2, 0, 0, 0);
    }

    float4v accs[3] = {acc0, acc1, acc2};
    #pragma unroll
    for (int t = 0; t < 3; ++t) {
        int ct = wave * 3 + t;
        int m = ct >> 2, hcol = (ct & 3) * 16 + c;
        if (m == 2) {
            // vT[b][hcol][t_global]
            #pragma unroll
            for (int j = 0; j < 4; ++j) {
                int r = row0 + g * 4 + j;
                vto[((size_t)(r >> 12) * 64 + hcol) * 4096 + (r & 4095)] = f32_to_bf16(accs[t][j]);
            }
        } else {
            unsigned short* dst = (m == 0) ? qo : ko;
            float sc = (m == 0) ? 0.125f : 1.0f;   // fold 1/sqrt(64) into q
            #pragma unroll
            for (int j = 0; j < 4; ++j)
                dst[(size_t)(row0 + g * 4 + j) * 64 + hcol] = f32_to_bf16(accs[t][j] * sc);
        }
    }
}

// ---------------- kernel 2: causal flash attention ----------------
// 8 waves/block: wave = qh + 2*slice. Each (qh,slice) wave runs online softmax
// over tiles t ≡ slice (mod 4) of its 16 q-rows, directly from global (K/vT are
// L2-resident). Slices combined at the end via LDS. No main-loop barriers.
#define PLD 72

__global__ __launch_bounds__(512) void attn_kernel(
    const unsigned short* __restrict__ qi, const unsigned short* __restrict__ ki,
    const unsigned short* __restrict__ vt, float* __restrict__ out)
{
    __shared__ __align__(16) unsigned short Ps[8][16 * PLD];  // per-wave P buffer
    __shared__ float CombO[6][16][64];                        // slices 1..3 x qh 0..1
    __shared__ float CombM[6][16];
    __shared__ float CombL[6][16];

    const int tid   = threadIdx.x;
    const int wave  = tid >> 6, lane = tid & 63;
    const int qh    = wave & 1, slice = wave >> 1;
    const int g = lane >> 4, c = lane & 15;

    // balanced qb pairing: CU's two co-resident blocks get qb and 127-qb
    const int bid = (int)blockIdx.x;
    const int u = bid & 255, v = bid >> 8;
    const int batch = (u >> 7) + (v << 1);
    const int qb = v ? (127 - (u & 127)) : (u & 127);

    const int rbase = qb * 32 + qh * 16;
    const size_t bo = (size_t)batch * T_LEN * HSZ;

    short8v qf0 = *(const short8v*)(qi + bo + (size_t)(rbase + c) * 64 +  0 + g * 8);
    short8v qf1 = *(const short8v*)(qi + bo + (size_t)(rbase + c) * 64 + 32 + g * 8);

    float4v acc[4];
    #pragma unroll
    for (int i2 = 0; i2 < 4; ++i2) acc[i2] = (float4v){0,0,0,0};
    float mrow[4] = {-3e38f, -3e38f, -3e38f, -3e38f};
    float lsum[4] = {0.f, 0.f, 0.f, 0.f};

    const int nt_w = ((rbase + 15) >> 6) + 1;   // tiles needed by this wave's rows
    unsigned short* Pw = &Ps[wave][0];

    for (int t = slice; t < nt_w; t += 4) {
        const int s0 = t * 64;

        // ---- S = Q K^T : B-frags straight from global K (L2-resident) ----
        float4v sa[4];
        #pragma unroll
        for (int ct = 0; ct < 4; ++ct) {
            const unsigned short* krow = ki + bo + (size_t)(s0 + ct * 16 + c) * 64;
            short8v b0 = *(const short8v*)(krow +  0 + g * 8);
            short8v b1 = *(const short8v*)(krow + 32 + g * 8);
            float4v z = {0, 0, 0, 0};
            z = __builtin_amdgcn_mfma_f32_16x16x32_bf16(qf0, b0, z, 0, 0, 0);
            sa[ct] = __builtin_amdgcn_mfma_f32_16x16x32_bf16(qf1, b1, z, 0, 0, 0);
        }

        // ---- issue first half of vT B-frags (latency hides under softmax) ----
        short8v vf0[4];
        #pragma unroll
        for (int ct = 0; ct < 4; ++ct)
            vf0[ct] = *(const short8v*)(vt + bo + (size_t)(ct * 16 + c) * 4096 + s0 + 0 + g * 8);

        // ---- causal mask ----
        if (s0 + 63 > rbase) {
            #pragma unroll
            for (int ct = 0; ct < 4; ++ct)
                #pragma unroll
                for (int j = 0; j < 4; ++j)
                    if (s0 + ct * 16 + c > rbase + g * 4 + j) sa[ct][j] = -3e38f;
        }

        // ---- online softmax (cross-lane sum deferred) ----
        #pragma unroll
        for (int j = 0; j < 4; ++j) {
            float mx = fmaxf(fmaxf(sa[0][j], sa[1][j]), fmaxf(sa[2][j], sa[3][j]));
            #pragma unroll
            for (int sh = 1; sh < 16; sh <<= 1) mx = fmaxf(mx, __shfl_xor(mx, sh, 64));
            const float nm = fmaxf(mrow[j], mx);
            const float al = __expf(mrow[j] - nm);
            mrow[j] = nm;
            float ps = 0.f;
            #pragma unroll
            for (int ct = 0; ct < 4; ++ct) {
                float p = __expf(sa[ct][j] - nm);
                sa[ct][j] = p;
                ps += p;
            }
            lsum[j] = lsum[j] * al + ps;
            #pragma unroll
            for (int ct = 0; ct < 4; ++ct) acc[ct][j] *= al;
        }

        // ---- P (D-layout) -> per-wave LDS -> A-fragment layout ----
        #pragma unroll
        for (int ct = 0; ct < 4; ++ct)
            #pragma unroll
            for (int j = 0; j < 4; ++j)
                Pw[(g * 4 + j) * PLD + ct * 16 + c] = f32_to_bf16(sa[ct][j]);

        // ---- second half of vT B-frags (hides under P roundtrip) ----
        short8v vf1[4];
        #pragma unroll
        for (int ct = 0; ct < 4; ++ct)
            vf1[ct] = *(const short8v*)(vt + bo + (size_t)(ct * 16 + c) * 4096 + s0 + 32 + g * 8);

        short8v pa0 = *(const short8v*)(&Pw[c * PLD +  0 + g * 8]);
        short8v pa1 = *(const short8v*)(&Pw[c * PLD + 32 + g * 8]);

        // ---- O += P V ----
        #pragma unroll
        for (int ct = 0; ct < 4; ++ct)
            acc[ct] = __builtin_amdgcn_mfma_f32_16x16x32_bf16(pa0, vf0[ct], acc[ct], 0, 0, 0);
        #pragma unroll
        for (int ct = 0; ct < 4; ++ct)
            acc[ct] = __builtin_amdgcn_mfma_f32_16x16x32_bf16(pa1, vf1[ct], acc[ct], 0, 0, 0);
    }

    // ---- per-wave: reduce row sums across the 16 c-lanes ----
    #pragma unroll
    for (int j = 0; j < 4; ++j) {
        float l = lsum[j];
        #pragma unroll
        for (int sh = 1; sh < 16; sh <<= 1) l += __shfl_xor(l, sh, 64);
        lsum[j] = l;   // uniform across lanes now
    }

    // ---- cross-slice combine ----
    if (slice > 0) {
        const int sidx = (slice - 1) * 2 + qh;
        #pragma unroll
        for (int ct = 0; ct < 4; ++ct)
            #pragma unroll
            for (int j = 0; j < 4; ++j)
                CombO[sidx][g * 4 + j][ct * 16 + c] = acc[ct][j];
        if (c == 0) {
            #pragma unroll
            for (int j = 0; j < 4; ++j) {
                CombM[sidx][g * 4 + j] = mrow[j];
                CombL[sidx][g * 4 + j] = lsum[j];
            }
        }
    }
    __syncthreads();

    if (slice == 0) {
        float a0[4], as[3][4], linv[4];
        #pragma unroll
        for (int j = 0; j < 4; ++j) {
            const int r = g * 4 + j;
            float M = mrow[j];
            #pragma unroll
            for (int s = 0; s < 3; ++s) M = fmaxf(M, CombM[s * 2 + qh][r]);
            a0[j] = __expf(mrow[j] - M);
            float lt = lsum[j] * a0[j];
            #pragma unroll
            for (int s = 0; s < 3; ++s) {
                as[s][j] = __expf(CombM[s * 2 + qh][r] - M);
                lt += as[s][j] * CombL[s * 2 + qh][r];
            }
            linv[j] = 1.0f / lt;
        }
        #pragma unroll
        for (int ct = 0; ct < 4; ++ct)
            #pragma unroll
            for (int j = 0; j < 4; ++j) {
                const int r = g * 4 + j;
                float o = acc[ct][j] * a0[j];
                #pragma unroll
                for (int s = 0; s < 3; ++s)
                    o += as[s][j] * CombO[s * 2 + qh][r][ct * 16 + c];
                out[bo + (size_t)(rbase + r) * 64 + ct * 16 + c] = o * linv[j];
            }
    }
}

extern "C" void kernel_launch(void* const* d_in, const int* in_sizes, int n_in,
                              void* d_out, int out_size, void* d_ws, size_t ws_size,
                              hipStream_t stream) {
    const float* x  = (const float*)d_in[0];
    const float* Wq = (const float*)d_in[1];
    const float* Wk = (const float*)d_in[2];
    const float* Wv = (const float*)d_in[3];

    unsigned short* Wt = (unsigned short*)d_ws;                        // 384 KiB
    unsigned short* q  = (unsigned short*)((char*)d_ws + (size_t)3 * 65536 * 2);
    unsigned short* k  = q + (size_t)4 * T_LEN * HSZ;
    unsigned short* vT = k + (size_t)4 * T_LEN * HSZ;                  // [B][64][4096]
    float* out = (float*)d_out;

    hipLaunchKernelGGL(wt_kernel,  dim3(768), dim3(256), 0, stream, Wq, Wk, Wv, Wt);
    hipLaunchKernelGGL(qkv_kernel, dim3(1024), dim3(256), 0, stream, x, Wt, q, k, vT);
    hipLaunchKernelGGL(attn_kernel, dim3(512), dim3(512), 0, stream, q, k, vT, out);
}